// Round 4
// baseline (290.726 us; speedup 1.0000x reference)
//
#include <hip/hip_runtime.h>
#include <math.h>

#define DIM 24
#define HID 256
#define NLO 276
#define NSAMP 4096
// output layout: M [4096*576] | c [4096*24] | g [4096*24]
#define C_OFF 2359296
#define G_OFF 2457600

// workspace layout (float offsets)
#define OFF_W2FH 0          // bf16 hi, W2 MFMA-A frags (65536 sh)   32768 f
#define OFF_W2FL 32768      // bf16 lo
#define OFF_WEFH 65536      // bf16 hi, [WLd;WLo;0] frags (81920 sh) 40960 f
#define OFF_WEFL 106496
#define OFF_W1H16 147456    // f16 hi, W1 frags (8192 sh)            4096 f
#define OFF_W1L16 151552    // f16 lo*4096
#define OFF_W2H16 155648    // f16 hi, W2 frags (65536 sh)           32768 f
#define OFF_W2L16 188416
#define OFF_WHH16 221184    // f16 hi, heads (Ld|G|Lo|0) frags (86016 sh) 43008 f
#define OFF_WHL16 264192
#define OFF_REC  307200     // per-sample record, stride 364 floats:
                            // [0..16) msk u32, [16..40) sig, [40..64) u, [64..88) Ld, [88..364) lo
#define REC_STRIDE 364

typedef __attribute__((ext_vector_type(8))) short bf16x8;
typedef __attribute__((ext_vector_type(8))) _Float16 f16x8;
typedef __attribute__((ext_vector_type(4))) float f32x4;

__device__ __forceinline__ float leaky(float x){ return x > 0.f ? x : 0.01f*x; }
__device__ __forceinline__ unsigned short f2b(float f){           // fp32 -> bf16 RNE
  unsigned u = __float_as_uint(f);
  return (unsigned short)((u + 0x7FFFu + ((u >> 16) & 1u)) >> 16);
}
__device__ __forceinline__ float b2f(unsigned short h){ return __uint_as_float(((unsigned)h) << 16); }
__device__ __forceinline__ void f2h2(float v, unsigned short* hi, unsigned short* lo){
  _Float16 h = (_Float16)v;
  _Float16 l = (_Float16)((v - (float)h) * 4096.f);
  *hi = *(unsigned short*)&h; *lo = *(unsigned short*)&l;
}

// ---------------- Kernel 0: fragment packing ----------------
__global__ __launch_bounds__(256) void k0_prep(
    const float* __restrict__ W1, const float* __restrict__ W2,
    const float* __restrict__ WG, const float* __restrict__ WLd,
    const float* __restrict__ WLo, float* __restrict__ ws)
{
  const int tid = blockIdx.x*256 + threadIdx.x;
  const int nth = gridDim.x*256;
  // frag geometry (16x16x32 A): m = mt*16+(l&15), k = kb*32+((l>>4)&3)*8+j
  unsigned short* W2FH = (unsigned short*)(ws + OFF_W2FH);
  unsigned short* W2FL = (unsigned short*)(ws + OFF_W2FL);
  for (int e = tid; e < 65536; e += nth){
    int j=e&7, l=(e>>3)&63, kb=(e>>9)&7, mt=e>>12;
    int m = mt*16+(l&15), k = kb*32+((l>>4)&3)*8+j;
    float v = W2[m*256+k];
    unsigned short h = f2b(v);
    W2FH[e]=h; W2FL[e]=f2b(v-b2f(h));
  }
  unsigned short* WEFH = (unsigned short*)(ws + OFF_WEFH);
  unsigned short* WEFL = (unsigned short*)(ws + OFF_WEFL);
  for (int e = tid; e < 81920; e += nth){
    int j=e&7, l=(e>>3)&63, kb=(e>>9)&7, mt=e>>12;
    int r = mt*16+(l&15), k = kb*32+((l>>4)&3)*8+j;
    float v = 0.f;
    if (r < 24) v = WLd[r*256+k]; else if (r < 300) v = WLo[(r-24)*256+k];
    unsigned short h = f2b(v);
    WEFH[e]=h; WEFL[e]=f2b(v-b2f(h));
  }
  unsigned short* W1H = (unsigned short*)(ws + OFF_W1H16);
  unsigned short* W1L = (unsigned short*)(ws + OFF_W1L16);
  for (int e = tid; e < 8192; e += nth){      // single kb, K=32 (24 + pad)
    int j=e&7, l=(e>>3)&63, mt=e>>9;
    int m = mt*16+(l&15), k = ((l>>4)&3)*8+j;
    float v = (k < 24) ? W1[m*24+k] : 0.f;
    f2h2(v, &W1H[e], &W1L[e]);
  }
  unsigned short* W2H = (unsigned short*)(ws + OFF_W2H16);
  unsigned short* W2L = (unsigned short*)(ws + OFF_W2L16);
  for (int e = tid; e < 65536; e += nth){
    int j=e&7, l=(e>>3)&63, kb=(e>>9)&7, mt=e>>12;
    int m = mt*16+(l&15), k = kb*32+((l>>4)&3)*8+j;
    f2h2(W2[m*256+k], &W2H[e], &W2L[e]);
  }
  unsigned short* WHH = (unsigned short*)(ws + OFF_WHH16);
  unsigned short* WHL = (unsigned short*)(ws + OFF_WHL16);
  for (int e = tid; e < 86016; e += nth){     // 21 M-tiles: rows (Ld|G|Lo|0)
    int j=e&7, l=(e>>3)&63, kb=(e>>9)&7, mt=e>>12;
    int rr = mt*16+(l&15), k = kb*32+((l>>4)&3)*8+j;
    float v = 0.f;
    if (rr < 24) v = WLd[rr*256+k];
    else if (rr < 48) v = WG[(rr-24)*256+k];
    else if (rr < 324) v = WLo[(rr-48)*256+k];
    f2h2(v, &WHH[e], &WHL[e]);
  }
}

// ---------------- Kernel 1: MFMA forward (32 samples/block) ----------------
// f16 scaled-split (hi + 4096*lo, separate accumulators) => ~fp32 accuracy for
// the pre-activations (mask decisions must match fp32 reference).
__global__ __launch_bounds__(256) void k1_fwd(
    const float* __restrict__ q, const float* __restrict__ qd_g,
    const float* __restrict__ b1, const float* __restrict__ b2,
    const float* __restrict__ bG, const float* __restrict__ bLd,
    const float* __restrict__ bLo, float* __restrict__ ws,
    float* __restrict__ out)
{
  const int s0 = blockIdx.x*32, t = threadIdx.x;
  const int w = t>>6, l = t&63, l15 = l&15, l4g = (l>>4)&3;
  float* REC = ws + OFF_REC;

  __shared__ __align__(16) char pool[33792];   // BQ (5120) -> BH2|BL2 (33792)
  __shared__ float qd_s[32][24];
  __shared__ float Ld_s[32][24];
  __shared__ unsigned char mb[32][64];
  unsigned short* BQH = (unsigned short*)pool;        // [32][40] f16
  unsigned short* BQL = BQH + 1280;
  unsigned short* BH2 = (unsigned short*)pool;        // [32][264] f16
  unsigned short* BL2 = BH2 + 8448;

  for (int f = t; f < 768; f += 256){
    float v = q[s0*24 + f];
    int n = f/24, k = f%24;
    f2h2(v, &BQH[n*40+k], &BQL[n*40+k]);
    ((float*)qd_s)[f] = qd_g[s0*24 + f];
  }
  { int n = t>>3, k = 24 + (t&7); BQH[n*40+k]=0; BQL[n*40+k]=0; }
  __syncthreads();

  // ---- phase A: h1 pre-acts = W1 @ qT ----
  f32x4 aH[4][2], aX[4][2];
  #pragma unroll
  for (int i=0;i<4;++i) for (int nt=0;nt<2;++nt){ aH[i][nt]=(f32x4){0,0,0,0}; aX[i][nt]=(f32x4){0,0,0,0}; }
  {
    const f16x8* WH = (const f16x8*)(ws + OFF_W1H16);
    const f16x8* WL = (const f16x8*)(ws + OFF_W1L16);
    f16x8 Af[4], Al[4], Bh[2], Bl[2];
    #pragma unroll
    for (int i=0;i<4;++i){ int mt=w+4*i; Af[i]=WH[mt*64+l]; Al[i]=WL[mt*64+l]; }
    #pragma unroll
    for (int nt=0;nt<2;++nt){
      int off=(nt*16+l15)*40 + l4g*8;
      Bh[nt]=*(const f16x8*)(BQH+off); Bl[nt]=*(const f16x8*)(BQL+off);
    }
    #pragma unroll
    for (int i=0;i<4;++i)
      #pragma unroll
      for (int nt=0;nt<2;++nt){
        aH[i][nt]=__builtin_amdgcn_mfma_f32_16x16x32_f16(Af[i],Bh[nt],aH[i][nt],0,0,0);
        aX[i][nt]=__builtin_amdgcn_mfma_f32_16x16x32_f16(Af[i],Bl[nt],aX[i][nt],0,0,0);
        aX[i][nt]=__builtin_amdgcn_mfma_f32_16x16x32_f16(Al[i],Bh[nt],aX[i][nt],0,0,0);
      }
  }
  __syncthreads();
  // epilogue A: bias, mask nibble, leaky, f16-split -> BH2
  #pragma unroll
  for (int i=0;i<4;++i){
    int m0=(w+4*i)*16+4*l4g;
    float4 bb = *(const float4*)(b1+m0);
    #pragma unroll
    for (int nt=0;nt<2;++nt){
      int n = nt*16+l15;
      unsigned nib=0; unsigned short hs[4], ls[4];
      #pragma unroll
      for (int r=0;r<4;++r){
        float val = aH[i][nt][r] + aX[i][nt][r]*(1.f/4096.f) + ((const float*)&bb)[r];
        if (val > 0.f) nib |= 1u<<r;
        f2h2(leaky(val), &hs[r], &ls[r]);
      }
      mb[n][(m0>>2)] = (unsigned char)nib;
      *(uint2*)(BH2 + n*264 + m0) = make_uint2((unsigned)hs[0]|((unsigned)hs[1]<<16),
                                               (unsigned)hs[2]|((unsigned)hs[3]<<16));
      *(uint2*)(BL2 + n*264 + m0) = make_uint2((unsigned)ls[0]|((unsigned)ls[1]<<16),
                                               (unsigned)ls[2]|((unsigned)ls[3]<<16));
    }
  }
  __syncthreads();
  { // assemble msk1 -> rec
    int n = t>>3, w8 = t&7; unsigned word = 0;
    #pragma unroll
    for (int b=0;b<8;++b) word |= (unsigned)(mb[n][w8*8+b] & 0xFu) << (4*b);
    ((unsigned*)(REC + (size_t)(s0+n)*REC_STRIDE))[w8] = word;
  }

  // ---- phase B: h2 = W2 @ h1 ----
  #pragma unroll
  for (int i=0;i<4;++i) for (int nt=0;nt<2;++nt){ aH[i][nt]=(f32x4){0,0,0,0}; aX[i][nt]=(f32x4){0,0,0,0}; }
  {
    const f16x8* WH = (const f16x8*)(ws + OFF_W2H16);
    const f16x8* WL = (const f16x8*)(ws + OFF_W2L16);
    for (int kb=0;kb<8;++kb){
      f16x8 Af[4], Al[4], Bh[2], Bl[2];
      #pragma unroll
      for (int i=0;i<4;++i){ int mt=w+4*i; Af[i]=WH[(mt*8+kb)*64+l]; Al[i]=WL[(mt*8+kb)*64+l]; }
      #pragma unroll
      for (int nt=0;nt<2;++nt){
        int off=(nt*16+l15)*264 + kb*32 + l4g*8;
        Bh[nt]=*(const f16x8*)(BH2+off); Bl[nt]=*(const f16x8*)(BL2+off);
      }
      #pragma unroll
      for (int i=0;i<4;++i)
        #pragma unroll
        for (int nt=0;nt<2;++nt){
          aH[i][nt]=__builtin_amdgcn_mfma_f32_16x16x32_f16(Af[i],Bh[nt],aH[i][nt],0,0,0);
          aX[i][nt]=__builtin_amdgcn_mfma_f32_16x16x32_f16(Af[i],Bl[nt],aX[i][nt],0,0,0);
          aX[i][nt]=__builtin_amdgcn_mfma_f32_16x16x32_f16(Al[i],Bh[nt],aX[i][nt],0,0,0);
        }
    }
  }
  __syncthreads();           // all reads of h1 done
  #pragma unroll
  for (int i=0;i<4;++i){     // epilogue B (overwrite BH2 with h2)
    int m0=(w+4*i)*16+4*l4g;
    float4 bb = *(const float4*)(b2+m0);
    #pragma unroll
    for (int nt=0;nt<2;++nt){
      int n = nt*16+l15;
      unsigned nib=0; unsigned short hs[4], ls[4];
      #pragma unroll
      for (int r=0;r<4;++r){
        float val = aH[i][nt][r] + aX[i][nt][r]*(1.f/4096.f) + ((const float*)&bb)[r];
        if (val > 0.f) nib |= 1u<<r;
        f2h2(leaky(val), &hs[r], &ls[r]);
      }
      mb[n][(m0>>2)] = (unsigned char)nib;
      *(uint2*)(BH2 + n*264 + m0) = make_uint2((unsigned)hs[0]|((unsigned)hs[1]<<16),
                                               (unsigned)hs[2]|((unsigned)hs[3]<<16));
      *(uint2*)(BL2 + n*264 + m0) = make_uint2((unsigned)ls[0]|((unsigned)ls[1]<<16),
                                               (unsigned)ls[2]|((unsigned)ls[3]<<16));
    }
  }
  __syncthreads();
  { // assemble msk2 -> rec
    int n = t>>3, w8 = t&7; unsigned word = 0;
    #pragma unroll
    for (int b=0;b<8;++b) word |= (unsigned)(mb[n][w8*8+b] & 0xFu) << (4*b);
    ((unsigned*)(REC + (size_t)(s0+n)*REC_STRIDE))[8+w8] = word;
  }

  // ---- phase C: heads = [WLd;WG;WLo;0] @ h2, two passes of 3 M-tiles ----
  for (int pass=0; pass<2; ++pass){
    f32x4 cH[3][2], cX[3][2];
    #pragma unroll
    for (int i=0;i<3;++i) for (int nt=0;nt<2;++nt){ cH[i][nt]=(f32x4){0,0,0,0}; cX[i][nt]=(f32x4){0,0,0,0}; }
    const f16x8* WH = (const f16x8*)(ws + OFF_WHH16);
    const f16x8* WL = (const f16x8*)(ws + OFF_WHL16);
    for (int kb=0;kb<8;++kb){
      f16x8 Af[3], Al[3], Bh[2], Bl[2];
      #pragma unroll
      for (int i=0;i<3;++i){
        int mt = w + 4*(3*pass+i);
        if (mt < 21){ Af[i]=WH[(mt*8+kb)*64+l]; Al[i]=WL[(mt*8+kb)*64+l]; }
      }
      #pragma unroll
      for (int nt=0;nt<2;++nt){
        int off=(nt*16+l15)*264 + kb*32 + l4g*8;
        Bh[nt]=*(const f16x8*)(BH2+off); Bl[nt]=*(const f16x8*)(BL2+off);
      }
      #pragma unroll
      for (int i=0;i<3;++i){
        int mt = w + 4*(3*pass+i);
        if (mt < 21){
          #pragma unroll
          for (int nt=0;nt<2;++nt){
            cH[i][nt]=__builtin_amdgcn_mfma_f32_16x16x32_f16(Af[i],Bh[nt],cH[i][nt],0,0,0);
            cX[i][nt]=__builtin_amdgcn_mfma_f32_16x16x32_f16(Af[i],Bl[nt],cX[i][nt],0,0,0);
            cX[i][nt]=__builtin_amdgcn_mfma_f32_16x16x32_f16(Al[i],Bh[nt],cX[i][nt],0,0,0);
          }
        }
      }
    }
    // epilogue (writes only global + Ld_s; no LDS-overlay hazard)
    #pragma unroll
    for (int i=0;i<3;++i){
      int mt = w + 4*(3*pass+i);
      if (mt >= 21) continue;
      int m0 = mt*16+4*l4g;
      #pragma unroll
      for (int nt=0;nt<2;++nt){
        int n = nt*16+l15, sG = s0+n;
        float* recn = REC + (size_t)sG*REC_STRIDE;
        #pragma unroll
        for (int r=0;r<4;++r){
          int rr = m0+r;
          float val = cH[i][nt][r] + cX[i][nt][r]*(1.f/4096.f);
          if (rr < 24){
            val += bLd[rr];
            recn[16+rr] = 1.f/(1.f + expf(-val));
            float sp = fmaxf(val,0.f) + log1pf(expf(-fabsf(val)));
            recn[64+rr] = sp; Ld_s[n][rr] = sp;
          } else if (rr < 48){
            out[G_OFF + sG*24 + (rr-24)] = val + bG[rr-24];
          } else if (rr < 324){
            recn[88 + rr-48] = val + bLo[rr-48];
          }
        }
      }
    }
  }
  __syncthreads();

  // ---- u[c] = qd[c]*Ld[c] + sum_{r>c} qd[r]*lo[r(r-1)/2+c] ----
  for (int task=t; task<768; task+=256){
    int n = task/24, c = task%24;
    float* recn = REC + (size_t)(s0+n)*REC_STRIDE;
    float u = qd_s[n][c]*Ld_s[n][c];
    for (int r=c+1; r<24; ++r) u += qd_s[n][r]*recn[88 + r*(r-1)/2 + c];
    recn[40+c] = u;
  }
}

// ---------------- Kernel 2: L/M + MFMA Jacobian chain + c (2 samples/block) ----------------
__global__ __launch_bounds__(256, 2) void k2_jac(
    const float* __restrict__ q_dot, const float* __restrict__ W1g,
    float* __restrict__ ws, float* __restrict__ out)
{
  const int n0 = blockIdx.x*2, t = threadIdx.x;
  const int w = t >> 6, l = t & 63;
  const int l15 = l & 15, l4g = (l >> 4) & 3;
  float* REC = ws + OFF_REC;

  __shared__ __align__(16) char pool[58176];
  __shared__ float dld2v[1200];                 // [2][24*25]
  __shared__ float qd2[2][24], u2[2][24], sig2[2][24], dld_dt2[2][24], w12[2][24];
  __shared__ unsigned msk[2][16];
  float* Lp = (float*)pool;                     // phase0: [2][600] (stride 25)
  unsigned short* BH = (unsigned short*)pool;   // [48][264] bf16
  unsigned short* BL = BH + 12672;
  float* dlo2 = (float*)pool;                   // [2][276*25] = 55200 B
  float* dlo_dt2 = (float*)(pool + 55200);      // [2][276]
  float* qp = (float*)(pool + 57408);           // [4][48]

  if (t < 32) msk[t>>4][t&15] = ((const unsigned*)(REC + (size_t)(n0+(t>>4))*REC_STRIDE))[t&15];
  if (t < 48){
    int s = t/24, i = t%24;
    const float* rc = REC + (size_t)(n0+s)*REC_STRIDE;
    sig2[s][i] = rc[16+i]; u2[s][i] = rc[40+i]; qd2[s][i] = q_dot[(n0+s)*24+i];
  }
  // build L (stride 25)
  for (int e = t; e < 1152; e += 256){
    int s = e/576, rc = e%576, r = rc/24, c = rc%24;
    const float* rr = REC + (size_t)(n0+s)*REC_STRIDE;
    float v = 0.f;
    if (r == c) v = rr[64+r]; else if (r > c) v = rr[88 + r*(r-1)/2 + c];
    Lp[s*600 + r*25 + c] = v;
  }
  __syncthreads();
  // M = L L^T + 1e-9 I
  for (int e = t; e < 1152; e += 256){
    int s = e/576, rc = e%576, r = rc/24, c = rc%24, km = min(r,c);
    float acc = (r == c) ? 1e-9f : 0.f;
    const float* Ls = Lp + s*600;
    for (int k = 0; k <= km; ++k) acc += Ls[r*25+k]*Ls[c*25+k];
    out[(size_t)(n0+s)*576 + rc] = acc;
  }
  __syncthreads();

  // ---- Bd = dR1 ⊙ W1 (bf16 split), thread t owns k=t ----
  {
    float w1r[24];
    #pragma unroll
    for (int d = 0; d < 24; ++d) w1r[d] = W1g[t*24 + d];
    float dr0 = ((msk[0][t>>5] >> (t&31)) & 1u) ? 1.f : -0.01f;
    float dr1 = ((msk[1][t>>5] >> (t&31)) & 1u) ? 1.f : -0.01f;
    #pragma unroll
    for (int c = 0; c < 48; ++c){
      int s = c >= 24, d = c - 24*s;
      float f = (s ? dr1 : dr0) * w1r[d];
      unsigned short h = f2b(f);
      BH[c*264 + t] = h;
      BL[c*264 + t] = f2b(f - b2f(h));
    }
  }
  __syncthreads();

  // ---- Stage D: wave w -> M-tiles {4w..4w+3} x N-tiles {0,1,2} ----
  f32x4 accD[4][3];
  #pragma unroll
  for (int i = 0; i < 4; ++i)
    #pragma unroll
    for (int nt = 0; nt < 3; ++nt) accD[i][nt] = (f32x4){0.f,0.f,0.f,0.f};
  {
    const bf16x8* AHp = (const bf16x8*)(ws + OFF_W2FH);
    const bf16x8* ALp = (const bf16x8*)(ws + OFF_W2FL);
    for (int kb = 0; kb < 8; ++kb){
      bf16x8 AH[4], AL[4], BHf[3], BLf[3];
      #pragma unroll
      for (int i = 0; i < 4; ++i){
        int mt = 4*w + i;
        AH[i] = AHp[(mt*8+kb)*64 + l];
        AL[i] = ALp[(mt*8+kb)*64 + l];
      }
      #pragma unroll
      for (int nt = 0; nt < 3; ++nt){
        int off = (nt*16 + l15)*264 + kb*32 + l4g*8;
        BHf[nt] = *(const bf16x8*)(BH + off);
        BLf[nt] = *(const bf16x8*)(BL + off);
      }
      #pragma unroll
      for (int i = 0; i < 4; ++i)
        #pragma unroll
        for (int nt = 0; nt < 3; ++nt){
          accD[i][nt] = __builtin_amdgcn_mfma_f32_16x16x32_bf16(AH[i], BHf[nt], accD[i][nt], 0, 0, 0);
          accD[i][nt] = __builtin_amdgcn_mfma_f32_16x16x32_bf16(AH[i], BLf[nt], accD[i][nt], 0, 0, 0);
          accD[i][nt] = __builtin_amdgcn_mfma_f32_16x16x32_bf16(AL[i], BHf[nt], accD[i][nt], 0, 0, 0);
        }
    }
  }
  __syncthreads();

  // ---- epilogue D: scale by dR2, re-split, store J2 over Bd ----
  {
    #pragma unroll
    for (int i = 0; i < 4; ++i){
      int mt = 4*w + i;
      int m0 = mt*16 + 4*l4g;
      int bb = m0 & 31;
      #pragma unroll
      for (int nt = 0; nt < 3; ++nt){
        int c = nt*16 + l15;
        int s = c >= 24;
        unsigned word = msk[s][8 + (mt>>1)];
        unsigned short hs[4], ls[4];
        #pragma unroll
        for (int r = 0; r < 4; ++r){
          float sc = ((word >> (bb + r)) & 1u) ? 1.f : -0.01f;
          float v = sc * accD[i][nt][r];
          hs[r] = f2b(v); ls[r] = f2b(v - b2f(hs[r]));
        }
        *(uint2*)(BH + c*264 + m0) = make_uint2((unsigned)hs[0] | ((unsigned)hs[1]<<16),
                                                (unsigned)hs[2] | ((unsigned)hs[3]<<16));
        *(uint2*)(BL + c*264 + m0) = make_uint2((unsigned)ls[0] | ((unsigned)ls[1]<<16),
                                                (unsigned)ls[2] | ((unsigned)ls[3]<<16));
      }
    }
  }
  __syncthreads();

  // ---- Stage E: wave w -> M-tiles {5w..5w+4} x N-tiles {0,1,2} ----
  f32x4 accE[5][3];
  #pragma unroll
  for (int i = 0; i < 5; ++i)
    #pragma unroll
    for (int nt = 0; nt < 3; ++nt) accE[i][nt] = (f32x4){0.f,0.f,0.f,0.f};
  {
    const bf16x8* AHp = (const bf16x8*)(ws + OFF_WEFH);
    const bf16x8* ALp = (const bf16x8*)(ws + OFF_WEFL);
    for (int kb = 0; kb < 8; ++kb){
      bf16x8 AH[5], AL[5], BHf[3], BLf[3];
      #pragma unroll
      for (int i = 0; i < 5; ++i){
        int mt = 5*w + i;
        AH[i] = AHp[(mt*8+kb)*64 + l];
        AL[i] = ALp[(mt*8+kb)*64 + l];
      }
      #pragma unroll
      for (int nt = 0; nt < 3; ++nt){
        int off = (nt*16 + l15)*264 + kb*32 + l4g*8;
        BHf[nt] = *(const bf16x8*)(BH + off);
        BLf[nt] = *(const bf16x8*)(BL + off);
      }
      #pragma unroll
      for (int i = 0; i < 5; ++i)
        #pragma unroll
        for (int nt = 0; nt < 3; ++nt){
          accE[i][nt] = __builtin_amdgcn_mfma_f32_16x16x32_bf16(AH[i], BHf[nt], accE[i][nt], 0, 0, 0);
          accE[i][nt] = __builtin_amdgcn_mfma_f32_16x16x32_bf16(AH[i], BLf[nt], accE[i][nt], 0, 0, 0);
          accE[i][nt] = __builtin_amdgcn_mfma_f32_16x16x32_bf16(AL[i], BHf[nt], accE[i][nt], 0, 0, 0);
        }
    }
  }
  __syncthreads();

  // ---- epilogue E: scatter dld (sig-scaled) / dlo, stride-25 padded ----
  #pragma unroll
  for (int i = 0; i < 5; ++i){
    int mt = 5*w + i;
    #pragma unroll
    for (int nt = 0; nt < 3; ++nt){
      int c = nt*16 + l15;
      int s = c >= 24, d = c - 24*s;
      #pragma unroll
      for (int r = 0; r < 4; ++r){
        int re = mt*16 + 4*l4g + r;
        float v = accE[i][nt][r];
        if (re < 24) dld2v[s*600 + re*25 + d] = sig2[s][re]*v;
        else if (re < 300) dlo2[s*6900 + (re-24)*25 + d] = v;
      }
    }
  }
  __syncthreads();

  // ---- dlo_dt / dld_dt (conflict-free stride 25) ----
  for (int o2 = t; o2 < 552; o2 += 256){
    int s = o2/276, o = o2%276;
    float a = 0.f;
    #pragma unroll
    for (int d = 0; d < 24; ++d) a += dlo2[s*6900 + o*25 + d]*qd2[s][d];
    dlo_dt2[s*276 + o] = a;
  }
  if (t < 48){
    int s = t/24, i = t%24;
    float a = 0.f;
    #pragma unroll
    for (int d = 0; d < 24; ++d) a += dld2v[s*600 + i*25 + d]*qd2[s][d];
    dld_dt2[s][i] = a;
  }
  __syncthreads();

  // ---- quad partials (192 threads, 4 per (s,i)) + w1 (48 threads) ----
  if (t < 192){
    int g = t/48, si = t%48, s = si/24, i = si%24;
    int n = n0 + s;
    int m = (n*24 + i) & (NSAMP-1);              // faithful cross-sample index
    const float* qdm = q_dot + m*24;
    const float* um  = REC + (size_t)m*REC_STRIDE + 40;
    float part = 0.f;
    for (int c2 = g; c2 < 24; c2 += 4){
      float v = qdm[c2]*dld2v[s*600 + c2*25 + i];
      for (int r = c2+1; r < 24; ++r){
        int f = i*276 + r*(r-1)/2 + c2;          // faithful flat reinterpretation
        v += qdm[r]*dlo2[s*6900 + (f/24)*25 + (f%24)];
      }
      part += um[c2]*v;
    }
    qp[g*48 + si] = part;
  }
  if (t < 48){
    int s = t/24, i = t%24;
    float a = qd2[s][i]*dld_dt2[s][i];           // w1[i] = sum_j qd[j]*dLdt[j,i]
    for (int j = i+1; j < 24; ++j) a += qd2[s][j]*dlo_dt2[s*276 + j*(j-1)/2 + i];
    w12[s][i] = a;
  }
  __syncthreads();

  // ---- c ----
  if (t < 48){
    int s = t/24, i = t%24, n = n0 + s;
    const float* recn = REC + (size_t)n*REC_STRIDE;
    float cs = 0.f;
    for (int k = 0; k < i; ++k){
      float Lik = recn[88 + i*(i-1)/2 + k];
      cs += Lik*w12[s][k] + dlo_dt2[s*276 + i*(i-1)/2 + k]*u2[s][k];
    }
    cs += recn[64+i]*w12[s][i] + dld_dt2[s][i]*u2[s][i];
    float quad = qp[t] + qp[48+t] + qp[96+t] + qp[144+t];
    out[C_OFF + n*24 + i] = cs - quad;
  }
}

extern "C" void kernel_launch(void* const* d_in, const int* in_sizes, int n_in,
                              void* d_out, int out_size, void* d_ws, size_t ws_size,
                              hipStream_t stream)
{
  const float* q   = (const float*)d_in[0];
  const float* qd  = (const float*)d_in[1];
  const float* W1  = (const float*)d_in[2];
  const float* b1  = (const float*)d_in[3];
  const float* W2  = (const float*)d_in[4];
  const float* b2  = (const float*)d_in[5];
  const float* WG  = (const float*)d_in[6];
  const float* bG  = (const float*)d_in[7];
  const float* WLd = (const float*)d_in[8];
  const float* bLd = (const float*)d_in[9];
  const float* WLo = (const float*)d_in[10];
  const float* bLo = (const float*)d_in[11];
  float* out = (float*)d_out;
  float* ws  = (float*)d_ws;

  k0_prep<<<256, 256, 0, stream>>>(W1, W2, WG, WLd, WLo, ws);
  k1_fwd<<<NSAMP/32, 256, 0, stream>>>(q, qd, b1, b2, bG, bLd, bLo, ws, out);
  k2_jac<<<NSAMP/2, 256, 0, stream>>>(qd, W1, ws, out);
}